// Round 8
// baseline (37.371 us; speedup 1.0000x reference)
//
#include <hip/hip_runtime.h>

// MutualInformation2D: B=32 batches, N=2*512*512=524288 points/batch.
// R8: R2/R4 structure (simple tiled loads, 40 VGPR), single change: BPB=32.
// hist (per-block private, plain stores) -> mi (integer reduce + double MI)
// -> finalize (-mean). No global atomics anywhere -> deterministic.
//
// Read path is at the platform streaming-read ceiling (~4 TB/s): pure-load
// probe == full hist time; invariant to occupancy/NT/interleave/source.

#define BINS 32
#define NBINS2 1024
#define LDS_ROW 33                       // padded row stride
#define LDS_HIST (BINS * LDS_ROW)        // 1056
#define NBATCH 32
#define N_PER_BATCH (2 * 512 * 512)      // 524288 floats per batch
#define NVEC_BATCH (N_PER_BATCH / 4)     // 131072 float4 per batch
#define BPB 32                           // blocks per batch -> 1024 blocks
#define THREADS 256
#define TV 8                             // float4 per tile per array
#define NTILE (NVEC_BATCH / BPB / THREADS / TV)  // 2 tiles

__global__ __launch_bounds__(THREADS) void hist_kernel(const float* __restrict__ x,
                                                       const float* __restrict__ y,
                                                       unsigned* __restrict__ parts) {
    __shared__ unsigned h[LDS_HIST];
    for (int i = threadIdx.x; i < LDS_HIST; i += THREADS) h[i] = 0u;
    __syncthreads();

    const int b   = blockIdx.x / BPB;
    const int blk = blockIdx.x % BPB;
    const float4* xb = (const float4*)x + (size_t)b * NVEC_BATCH;
    const float4* yb = (const float4*)y + (size_t)b * NVEC_BATCH;

    // Block-cyclic interleave; each wave-load is a contiguous 1 KiB line.
    const int off = blk * THREADS + threadIdx.x;
    const int STRIDE = BPB * THREADS;    // 8192 float4

#pragma unroll
    for (int t = 0; t < NTILE; ++t) {
        // 16 independent float4 loads in flight (static indices -> VGPRs).
        float4 xa[TV], ya[TV];
#pragma unroll
        for (int j = 0; j < TV; ++j) xa[j] = xb[(size_t)(t * TV + j) * STRIDE + off];
#pragma unroll
        for (int j = 0; j < TV; ++j) ya[j] = yb[(size_t)(t * TV + j) * STRIDE + off];

#pragma unroll
        for (int j = 0; j < TV; ++j) {
            float ax[4] = {xa[j].x, xa[j].y, xa[j].z, xa[j].w};
            float ty[4] = {ya[j].x, ya[j].y, ya[j].z, ya[j].w};
#pragma unroll
            for (int k = 0; k < 4; ++k) {
                // Exact float32 replication of the reference binning.
                float u = (ax[k] + 1.0f) * 0.5f;
                float v = (ty[k] + 1.0f) * 0.5f;
                bool ok = (u >= 0.0f) & (u <= 1.0f) & (v >= 0.0f) & (v <= 1.0f);
                if (ok) {
                    int iu = (int)(u * 32.0f); if (iu > 31) iu = 31;
                    int iv = (int)(v * 32.0f); if (iv > 31) iv = 31;
                    atomicAdd(&h[iu * LDS_ROW + iv], 1u);
                }
            }
        }
    }
    __syncthreads();

    // Plain coalesced stores of the private histogram — no global atomics.
    unsigned* g = parts + (size_t)blockIdx.x * NBINS2;
    for (int i = threadIdx.x; i < NBINS2; i += THREADS)
        g[i] = h[(i >> 5) * LDS_ROW + (i & 31)];
}

__global__ __launch_bounds__(1024) void mi_kernel(const unsigned* __restrict__ parts,
                                                  double* __restrict__ mi_out) {
    __shared__ unsigned c[NBINS2];
    __shared__ unsigned px[BINS];
    __shared__ unsigned py[BINS];
    __shared__ double red[16];

    const int b = blockIdx.x;
    // Reduce partials: thread i owns bin i. Integer adds -> order-independent.
    const unsigned* base = parts + (size_t)b * BPB * NBINS2 + threadIdx.x;
    unsigned s = 0;
#pragma unroll
    for (int p = 0; p < BPB; ++p) s += base[(size_t)p * NBINS2];
    c[threadIdx.x] = s;
    __syncthreads();

    if (threadIdx.x < 32) {
        unsigned r = 0;
        for (int j = 0; j < 32; ++j) r += c[threadIdx.x * BINS + j];
        px[threadIdx.x] = r;
    } else if (threadIdx.x < 64) {
        int col = threadIdx.x - 32;
        unsigned r = 0;
        for (int j = 0; j < 32; ++j) r += c[j * BINS + col];
        py[col] = r;
    }
    __syncthreads();

    unsigned total = 0;
    for (int j = 0; j < 32; ++j) total += px[j];
    const double T = (double)total;

    double acc = 0.0;
    {
        unsigned cc = c[threadIdx.x];
        if (cc) {
            int r = threadIdx.x >> 5, col = threadIdx.x & 31;
            acc = (double)cc * log((double)cc * T / ((double)px[r] * (double)py[col]));
        }
    }
    // wave (64-lane) shuffle reduction, fixed order -> deterministic
    for (int off = 32; off > 0; off >>= 1)
        acc += __shfl_down(acc, off, 64);
    int wave = threadIdx.x >> 6;
    if ((threadIdx.x & 63) == 0) red[wave] = acc;
    __syncthreads();
    if (threadIdx.x == 0) {
        double t = 0.0;
        for (int i = 0; i < 16; ++i) t += red[i];
        mi_out[b] = t / T;
    }
}

__global__ void finalize_kernel(const double* __restrict__ mi, float* __restrict__ out) {
    if (threadIdx.x == 0) {
        double s = 0.0;
        for (int i = 0; i < NBATCH; ++i) s += mi[i];
        out[0] = (float)(-s / (double)NBATCH);
    }
}

extern "C" void kernel_launch(void* const* d_in, const int* in_sizes, int n_in,
                              void* d_out, int out_size, void* d_ws, size_t ws_size,
                              hipStream_t stream) {
    const float* x = (const float*)d_in[0];
    const float* y = (const float*)d_in[1];
    float* out = (float*)d_out;

    unsigned* parts = (unsigned*)d_ws;   // 32*32*1024*4 = 4 MiB
    double* mi = (double*)((char*)d_ws + (size_t)NBATCH * BPB * NBINS2 * sizeof(unsigned));

    hist_kernel<<<NBATCH * BPB, THREADS, 0, stream>>>(x, y, parts);
    mi_kernel<<<NBATCH, 1024, 0, stream>>>(parts, mi);
    finalize_kernel<<<1, 64, 0, stream>>>(mi, out);
}

// Round 9
// 34.335 us; speedup vs baseline: 1.0884x; 1.0884x over previous
//
#include <hip/hip_runtime.h>

// MutualInformation2D: B=32 batches, N=2*512*512=524288 points/batch.
// R9: R4 structure (BPB=64, simple tiled loads), single change: u16 partials
// (max 8192 counts/block < 65535 -> always safe), halving partials traffic.
// hist (per-block private, plain stores) -> mi (integer reduce + double MI)
// -> finalize (-mean). No global atomics anywhere -> deterministic.
//
// Read path is at the platform streaming-read ceiling (~4.3 TB/s read-only,
// above m13's per-direction copy rate): pure-load probe == full hist time;
// invariant to occupancy/NT/interleave/source (L3-resident replays equal).

#define BINS 32
#define NBINS2 1024
#define LDS_ROW 33                       // padded row stride
#define LDS_HIST (BINS * LDS_ROW)        // 1056
#define NBATCH 32
#define N_PER_BATCH (2 * 512 * 512)      // 524288 floats per batch
#define NVEC_BATCH (N_PER_BATCH / 4)     // 131072 float4 per batch
#define BPB 64                           // blocks per batch -> 2048 blocks
#define THREADS 256
#define VPT 8                            // float4 per thread per array

__global__ __launch_bounds__(THREADS) void hist_kernel(const float* __restrict__ x,
                                                       const float* __restrict__ y,
                                                       unsigned short* __restrict__ parts) {
    __shared__ unsigned h[LDS_HIST];
    for (int i = threadIdx.x; i < LDS_HIST; i += THREADS) h[i] = 0u;
    __syncthreads();

    const int b   = blockIdx.x >> 6;     // / BPB
    const int blk = blockIdx.x & 63;     // % BPB
    const float4* xb = (const float4*)x + (size_t)b * NVEC_BATCH;
    const float4* yb = (const float4*)y + (size_t)b * NVEC_BATCH;

    // Block-cyclic interleave; each wave-load is a contiguous 1 KiB line.
    const int off = blk * THREADS + threadIdx.x;
    float4 xa[VPT], ya[VPT];
#pragma unroll
    for (int j = 0; j < VPT; ++j) xa[j] = xb[(size_t)j * (BPB * THREADS) + off];
#pragma unroll
    for (int j = 0; j < VPT; ++j) ya[j] = yb[(size_t)j * (BPB * THREADS) + off];

#pragma unroll
    for (int j = 0; j < VPT; ++j) {
        float ax[4] = {xa[j].x, xa[j].y, xa[j].z, xa[j].w};
        float ty[4] = {ya[j].x, ya[j].y, ya[j].z, ya[j].w};
#pragma unroll
        for (int k = 0; k < 4; ++k) {
            // Exact float32 replication of the reference binning.
            float u = (ax[k] + 1.0f) * 0.5f;
            float v = (ty[k] + 1.0f) * 0.5f;
            bool ok = (u >= 0.0f) & (u <= 1.0f) & (v >= 0.0f) & (v <= 1.0f);
            if (ok) {
                int iu = (int)(u * 32.0f); if (iu > 31) iu = 31;
                int iv = (int)(v * 32.0f); if (iv > 31) iv = 31;
                atomicAdd(&h[iu * LDS_ROW + iv], 1u);
            }
        }
    }
    __syncthreads();

    // Packed u16 stores (2 bins/thread-store) — no global atomics.
    unsigned* g = (unsigned*)(parts + (size_t)blockIdx.x * NBINS2);
    for (int i = threadIdx.x; i < NBINS2 / 2; i += THREADS) {
        unsigned lo = h[((2 * i) >> 5) * LDS_ROW + ((2 * i) & 31)];
        unsigned hi = h[((2 * i + 1) >> 5) * LDS_ROW + ((2 * i + 1) & 31)];
        g[i] = (hi << 16) | lo;          // counts <= 8192 always fit u16
    }
}

__global__ __launch_bounds__(1024) void mi_kernel(const unsigned short* __restrict__ parts,
                                                  double* __restrict__ mi_out) {
    __shared__ unsigned c[NBINS2];
    __shared__ unsigned px[BINS];
    __shared__ unsigned py[BINS];
    __shared__ double red[16];

    const int b = blockIdx.x;
    // Reduce partials: thread i owns bin i. Integer adds -> order-independent.
    const unsigned short* base = parts + (size_t)b * BPB * NBINS2 + threadIdx.x;
    unsigned s = 0;
#pragma unroll
    for (int p = 0; p < BPB; ++p) s += base[(size_t)p * NBINS2];
    c[threadIdx.x] = s;
    __syncthreads();

    if (threadIdx.x < 32) {
        unsigned r = 0;
        for (int j = 0; j < 32; ++j) r += c[threadIdx.x * BINS + j];
        px[threadIdx.x] = r;
    } else if (threadIdx.x < 64) {
        int col = threadIdx.x - 32;
        unsigned r = 0;
        for (int j = 0; j < 32; ++j) r += c[j * BINS + col];
        py[col] = r;
    }
    __syncthreads();

    unsigned total = 0;
    for (int j = 0; j < 32; ++j) total += px[j];
    const double T = (double)total;

    double acc = 0.0;
    {
        unsigned cc = c[threadIdx.x];
        if (cc) {
            int r = threadIdx.x >> 5, col = threadIdx.x & 31;
            acc = (double)cc * log((double)cc * T / ((double)px[r] * (double)py[col]));
        }
    }
    // wave (64-lane) shuffle reduction, fixed order -> deterministic
    for (int off = 32; off > 0; off >>= 1)
        acc += __shfl_down(acc, off, 64);
    int wave = threadIdx.x >> 6;
    if ((threadIdx.x & 63) == 0) red[wave] = acc;
    __syncthreads();
    if (threadIdx.x == 0) {
        double t = 0.0;
        for (int i = 0; i < 16; ++i) t += red[i];
        mi_out[b] = t / T;
    }
}

__global__ void finalize_kernel(const double* __restrict__ mi, float* __restrict__ out) {
    if (threadIdx.x == 0) {
        double s = 0.0;
        for (int i = 0; i < NBATCH; ++i) s += mi[i];
        out[0] = (float)(-s / (double)NBATCH);
    }
}

extern "C" void kernel_launch(void* const* d_in, const int* in_sizes, int n_in,
                              void* d_out, int out_size, void* d_ws, size_t ws_size,
                              hipStream_t stream) {
    const float* x = (const float*)d_in[0];
    const float* y = (const float*)d_in[1];
    float* out = (float*)d_out;

    unsigned short* parts = (unsigned short*)d_ws;   // 32*64*1024*2 = 4 MiB
    double* mi = (double*)((char*)d_ws + (size_t)NBATCH * BPB * NBINS2 * sizeof(unsigned short));

    hist_kernel<<<NBATCH * BPB, THREADS, 0, stream>>>(x, y, parts);
    mi_kernel<<<NBATCH, 1024, 0, stream>>>(parts, mi);
    finalize_kernel<<<1, 64, 0, stream>>>(mi, out);
}